// Round 5
// baseline (401.985 us; speedup 1.0000x reference)
//
#include <hip/hip_runtime.h>
#include <hip/hip_bf16.h>

typedef unsigned short u16;
typedef __attribute__((ext_vector_type(8))) short bf16x8;
typedef __attribute__((ext_vector_type(4))) float f32x4;
typedef __attribute__((ext_vector_type(8))) u16 u16x8;
typedef __attribute__((ext_vector_type(4))) u16 u16x4;

#define T_SEQ 2048
#define HID 4096
#define NQ 32
#define NKV 8
#define DH 128
#define WIN 1024

__device__ __forceinline__ u16 f2bf(float f) {
  union { float f; unsigned int u; } v; v.f = f;
  unsigned int u = v.u;
  unsigned int r = (u + 0x7FFFu + ((u >> 16) & 1u)) >> 16;
  return (u16)r;
}

__device__ __forceinline__ void gload16(const void* g, void* l) {
  __builtin_amdgcn_global_load_lds(
      (const __attribute__((address_space(1))) unsigned int*)g,
      (__attribute__((address_space(3))) unsigned int*)l, 16, 0, 0);
}

// ---------------- elementwise f32 -> bf16 ----------------
__global__ __launch_bounds__(256) void f32_to_bf16(const float* __restrict__ in,
                                                   u16* __restrict__ out, int n) {
  int i = (blockIdx.x * 256 + threadIdx.x) * 8;
  if (i >= n) return;
  float4 a = *(const float4*)(in + i);
  float4 b = *(const float4*)(in + i + 4);
  u16x8 r;
  r[0] = f2bf(a.x); r[1] = f2bf(a.y); r[2] = f2bf(a.z); r[3] = f2bf(a.w);
  r[4] = f2bf(b.x); r[5] = f2bf(b.y); r[6] = f2bf(b.z); r[7] = f2bf(b.w);
  *(u16x8*)(out + i) = r;
}

// ---------------- tiled transpose f32 (R x C) -> bf16 (C x R) ----------------
__global__ __launch_bounds__(256) void transpose_f32_to_bf16(const float* __restrict__ in,
                                                             u16* __restrict__ out,
                                                             int R, int C) {
  __shared__ float tile[32][33];
  int c0 = blockIdx.x * 32, r0 = blockIdx.y * 32;
  int tx = threadIdx.x, ty = threadIdx.y;
  for (int i = 0; i < 32; i += 8)
    tile[ty + i][tx] = in[(size_t)(r0 + ty + i) * C + c0 + tx];
  __syncthreads();
  for (int i = 0; i < 32; i += 8)
    out[(size_t)(c0 + ty + i) * R + r0 + tx] = f2bf(tile[tx][ty + i]);
}

// ---------------- 256x256 GEMM, one-ahead-read windowed pipeline ----------------
// C(f32 MxN) = A(bf16 MxK rm) * Bt(bf16 NxK rm)^T, K-slice [kt0*64,(kt0+NT)*64)
// BK=64, 2-buf LDS (128KB), 8 waves 2Mx4N, per-wave 128x64, one barrier/window.
// Window W of tile t: {ds_reads for NEXT quadrant | one stage | 16 MFMA (regs
// from last window) | lgkmcnt(0) | [vmcnt(4) @W3] | s_barrier}.
// Reads (one ahead): W1->bfr1(t), W2->afB(t), W4->afA+bfr0(t+1).
// Stages (2-tile lead, into slot b=t&1 itself; units dead by then):
//   W2->B0(t+2), W3->A0(t+2), W4->A1(t+2)+B1(t+2).
// vmcnt(4) @end-W3(t) retires exactly {B0,A0,A1,B1}(t+1) (lead >= 3 windows).
// Tail stages clamp to NT-1 (dummy) to keep counts exact.
__global__ __launch_bounds__(512, 2) void gemm8p(const u16* __restrict__ A,
                                                 const u16* __restrict__ Bt,
                                                 float* __restrict__ C,
                                                 float* __restrict__ Cp,
                                                 int N, int K, int NT, int MT) {
  __shared__ u16 lsA[2][2][8192];   // [slot][staging-half: rows 0-127 / 128-255]
  __shared__ u16 lsB[2][2][8192];
  const int tid = threadIdx.x;
  const int lane = tid & 63, w = tid >> 6;
  const int wm = w >> 2, wn = w & 3;
  const int l15 = lane & 15, l4 = lane >> 4;

  const int nwg = gridDim.x;
  const int cpx = nwg >> 3;
  const int bid = blockIdx.x;
  const int swz = (bid & 7) * cpx + (bid >> 3);
  const int bm = (swz % MT) * 256;
  const int bn = (swz / MT) * 256;
  const int kt0 = blockIdx.y * NT;
  float* __restrict__ dst = blockIdx.y ? Cp : C;

  auto stageH = [&](int mat, int half, int slot, int kt) {
    const u16* src = mat ? Bt : A;
    int base_row = (mat ? bn : bm) + half * 128;
    u16* d = mat ? lsB[slot][half] : lsA[slot][half];
#pragma unroll
    for (int c = 0; c < 2; ++c) {
      int ci = (w * 2 + c) * 64 + lane;     // 16B chunk 0..1023
      int r = ci >> 3, cp = ci & 7;
      int scp = cp ^ (r & 7);               // pre-swizzled source chunk
      gload16(src + (size_t)(base_row + r) * K + kt * 64 + scp * 8,
              (char*)d + (w * 2 + c) * 1024);
    }
  };
  auto rdA = [&](int slot, int mh, int fr, int ks) -> bf16x8 {
    int r = mh * 64 + fr * 16 + l15;
    int ch = (ks * 4 + l4) ^ (r & 7);
    return *(const bf16x8*)(lsA[slot][wm] + r * 64 + ch * 8);
  };
  auto rdB = [&](int slot, int nh, int g, int ks) -> bf16x8 {
    int r = (wn & 1) * 64 + nh * 32 + g * 16 + l15;
    int ch = (ks * 4 + l4) ^ (r & 7);
    return *(const bf16x8*)(lsB[slot][wn >> 1] + r * 64 + ch * 8);
  };

  f32x4 acc[8][4] = {};
  bf16x8 afA[4][2], afB[4][2], bfr0[2][2], bfr1[2][2];

  // prologue: stage tiles 0 and 1 fully (16 loads), t0-resident, t1 in flight
  stageH(1, 0, 0, kt0);     stageH(0, 0, 0, kt0);
  stageH(0, 1, 0, kt0);     stageH(1, 1, 0, kt0);
  stageH(1, 0, 1, kt0 + 1); stageH(0, 0, 1, kt0 + 1);
  stageH(0, 1, 1, kt0 + 1); stageH(1, 1, 1, kt0 + 1);
  asm volatile("s_waitcnt vmcnt(8)" ::: "memory");
  __builtin_amdgcn_s_barrier();
  // Q1(0) fragments
#pragma unroll
  for (int fr = 0; fr < 4; ++fr)
#pragma unroll
    for (int ks = 0; ks < 2; ++ks) afA[fr][ks] = rdA(0, 0, fr, ks);
#pragma unroll
  for (int g = 0; g < 2; ++g)
#pragma unroll
    for (int ks = 0; ks < 2; ++ks) bfr0[g][ks] = rdB(0, 0, g, ks);
  asm volatile("s_waitcnt lgkmcnt(0)" ::: "memory");
  __builtin_amdgcn_sched_barrier(0);

  for (int t = 0; t < NT; ++t) {
    const int b = t & 1;
    const int bo = b ^ 1;
    const int ktt = kt0 + ((t + 2 < NT) ? t + 2 : NT - 1);

    // ---- W1: reads bfr1(t); MFMA Q1 (afA x bfr0 -> acc[0..3][0..1]) ----
#pragma unroll
    for (int g = 0; g < 2; ++g)
#pragma unroll
      for (int ks = 0; ks < 2; ++ks) bfr1[g][ks] = rdB(b, 1, g, ks);
    __builtin_amdgcn_s_setprio(1);
#pragma unroll
    for (int fr = 0; fr < 4; ++fr)
#pragma unroll
      for (int g = 0; g < 2; ++g) {
        acc[fr][g] = __builtin_amdgcn_mfma_f32_16x16x32_bf16(afA[fr][0], bfr0[g][0], acc[fr][g], 0, 0, 0);
        acc[fr][g] = __builtin_amdgcn_mfma_f32_16x16x32_bf16(afA[fr][1], bfr0[g][1], acc[fr][g], 0, 0, 0);
      }
    __builtin_amdgcn_s_setprio(0);
    asm volatile("s_waitcnt lgkmcnt(0)" ::: "memory");
    __builtin_amdgcn_sched_barrier(0);
    __builtin_amdgcn_s_barrier();

    // ---- W2: reads afB(t); stage B0(t+2); MFMA Q2 (afA x bfr1 -> acc[0..3][2..3]) ----
#pragma unroll
    for (int fr = 0; fr < 4; ++fr)
#pragma unroll
      for (int ks = 0; ks < 2; ++ks) afB[fr][ks] = rdA(b, 1, fr, ks);
    stageH(1, 0, b, ktt);
    __builtin_amdgcn_s_setprio(1);
#pragma unroll
    for (int fr = 0; fr < 4; ++fr)
#pragma unroll
      for (int g = 0; g < 2; ++g) {
        acc[fr][2 + g] = __builtin_amdgcn_mfma_f32_16x16x32_bf16(afA[fr][0], bfr1[g][0], acc[fr][2 + g], 0, 0, 0);
        acc[fr][2 + g] = __builtin_amdgcn_mfma_f32_16x16x32_bf16(afA[fr][1], bfr1[g][1], acc[fr][2 + g], 0, 0, 0);
      }
    __builtin_amdgcn_s_setprio(0);
    asm volatile("s_waitcnt lgkmcnt(0)" ::: "memory");
    __builtin_amdgcn_sched_barrier(0);
    __builtin_amdgcn_s_barrier();

    // ---- W3: stage A0(t+2); MFMA Q3 (afB x bfr0 -> acc[4..7][0..1]); vmcnt(4) ----
    stageH(0, 0, b, ktt);
    __builtin_amdgcn_s_setprio(1);
#pragma unroll
    for (int fr = 0; fr < 4; ++fr)
#pragma unroll
      for (int g = 0; g < 2; ++g) {
        acc[4 + fr][g] = __builtin_amdgcn_mfma_f32_16x16x32_bf16(afB[fr][0], bfr0[g][0], acc[4 + fr][g], 0, 0, 0);
        acc[4 + fr][g] = __builtin_amdgcn_mfma_f32_16x16x32_bf16(afB[fr][1], bfr0[g][1], acc[4 + fr][g], 0, 0, 0);
      }
    __builtin_amdgcn_s_setprio(0);
    asm volatile("s_waitcnt vmcnt(4)" ::: "memory");   // {A0,A1,B0,B1}(t+1) resident
    __builtin_amdgcn_sched_barrier(0);
    __builtin_amdgcn_s_barrier();

    // ---- W4: reads afA+bfr0(t+1); stage A1(t+2)+B1(t+2); MFMA Q4 ----
#pragma unroll
    for (int fr = 0; fr < 4; ++fr)
#pragma unroll
      for (int ks = 0; ks < 2; ++ks) afA[fr][ks] = rdA(bo, 0, fr, ks);
#pragma unroll
    for (int g = 0; g < 2; ++g)
#pragma unroll
      for (int ks = 0; ks < 2; ++ks) bfr0[g][ks] = rdB(bo, 0, g, ks);
    stageH(0, 1, b, ktt);
    stageH(1, 1, b, ktt);
    __builtin_amdgcn_s_setprio(1);
#pragma unroll
    for (int fr = 0; fr < 4; ++fr)
#pragma unroll
      for (int g = 0; g < 2; ++g) {
        acc[4 + fr][2 + g] = __builtin_amdgcn_mfma_f32_16x16x32_bf16(afB[fr][0], bfr1[g][0], acc[4 + fr][2 + g], 0, 0, 0);
        acc[4 + fr][2 + g] = __builtin_amdgcn_mfma_f32_16x16x32_bf16(afB[fr][1], bfr1[g][1], acc[4 + fr][2 + g], 0, 0, 0);
      }
    __builtin_amdgcn_s_setprio(0);
    asm volatile("s_waitcnt lgkmcnt(0)" ::: "memory");
    __builtin_amdgcn_sched_barrier(0);
    __builtin_amdgcn_s_barrier();
  }

  asm volatile("s_waitcnt vmcnt(0)" ::: "memory");     // drain tail dummies

#pragma unroll
  for (int mf = 0; mf < 8; ++mf)
#pragma unroll
    for (int nf = 0; nf < 4; ++nf) {
      int row = bm + wm * 128 + mf * 16 + l4 * 4;
      int col = bn + wn * 64 + nf * 16 + l15;
      float* p = dst + (size_t)row * N + col;
      p[0] = acc[mf][nf][0];
      p[(size_t)N] = acc[mf][nf][1];
      p[2 * (size_t)N] = acc[mf][nf][2];
      p[3 * (size_t)N] = acc[mf][nf][3];
    }
}

// ---------------- split-K reduce: c += p ----------------
__global__ __launch_bounds__(256) void add_f32(float* __restrict__ c,
                                               const float* __restrict__ p, int n) {
  int i = (blockIdx.x * 256 + threadIdx.x) * 4;
  if (i >= n) return;
  float4 a = *(float4*)(c + i);
  float4 b = *(const float4*)(p + i);
  a.x += b.x; a.y += b.y; a.z += b.z; a.w += b.w;
  *(float4*)(c + i) = a;
}

// ---------------- RMSNorm + RoPE + layout (Q scaled; Q,K row-major per head; V transposed) -------
__global__ __launch_bounds__(256) void rope_kernel(const float* __restrict__ qkv,
                                                   const float* __restrict__ cosb,
                                                   const float* __restrict__ sinb,
                                                   const float* __restrict__ qw,
                                                   const float* __restrict__ kw,
                                                   u16* __restrict__ Qo,
                                                   u16* __restrict__ Ko,
                                                   u16* __restrict__ Vt) {
  int wid = threadIdx.x >> 6, lane = threadIdx.x & 63;
  int item = blockIdx.x * 4 + wid;          // item = t*48 + hid
  int t = item / 48, hid = item % 48;
  const float* x = qkv + (size_t)t * 6144 + hid * 128;
  float x1 = x[lane], x2 = x[lane + 64];
  if (hid < NQ + NKV) {
    float ss = x1 * x1 + x2 * x2;
    for (int off = 32; off; off >>= 1) ss += __shfl_xor(ss, off);
    float inv = rsqrtf(ss * (1.0f / 128.0f) + 1e-6f);
    const float* wn = (hid < NQ) ? qw : kw;
    float n1 = x1 * inv * wn[lane], n2 = x2 * inv * wn[lane + 64];
    float c1 = cosb[t * 128 + lane], s1 = sinb[t * 128 + lane];
    float c2 = cosb[t * 128 + lane + 64], s2 = sinb[t * 128 + lane + 64];
    float o1 = n1 * c1 - n2 * s1;
    float o2 = n2 * c2 + n1 * s2;
    if (hid < NQ) {
      const float scale = 0.08838834764831845f;  // fold 1/sqrt(128) into Q
      u16* q = Qo + ((size_t)hid * T_SEQ + t) * 128;
      q[lane] = f2bf(o1 * scale); q[lane + 64] = f2bf(o2 * scale);
    } else {
      int h = hid - NQ;
      u16* k = Ko + ((size_t)h * T_SEQ + t) * 128;
      k[lane] = f2bf(o1); k[lane + 64] = f2bf(o2);
    }
  } else {
    int h = hid - (NQ + NKV);
    Vt[((size_t)h * 128 + lane) * T_SEQ + t] = f2bf(x1);
    Vt[((size_t)h * 128 + lane + 64) * T_SEQ + t] = f2bf(x2);
  }
}

#define WAITVM4() asm volatile("s_waitcnt vmcnt(4)" ::: "memory")
#define WAITVM0() asm volatile("s_waitcnt vmcnt(0)" ::: "memory")

// ---------------- flash attention: 4 waves/block, QBLK=64, KBLK=32, LDS dbuf ----------------
__global__ __launch_bounds__(256) void attn_kernel(const u16* __restrict__ Q,
                                                   const u16* __restrict__ Kb,
                                                   const u16* __restrict__ Vt,
                                                   u16* __restrict__ O) {
  __shared__ u16 kls[2][32 * 128];   // swizzled: chunk16 ^= (row&7)
  __shared__ u16 vls[2][128 * 32];   // swizzled: chunk16 ^= ((d>>1)&3)
  __shared__ u16 plds[4][16 * 40];   // per-wave P buffer [16 q][32 k] pad to 40

  const int tid = threadIdx.x;
  const int lane = tid & 63, w = tid >> 6;
  const int l15 = lane & 15, l4 = lane >> 4;
  const int h = blockIdx.x;          // q head
  const int q0 = blockIdx.y * 64;    // block q base
  const int wq0 = q0 + w * 16;       // wave q base
  const int kvh = h >> 2;

  bf16x8 qf[4];
  {
    const u16* qrow = Q + ((size_t)h * T_SEQ + (wq0 + l15)) * DH;
    for (int ks = 0; ks < 4; ++ks)
      qf[ks] = *(const bf16x8*)(qrow + ks * 32 + l4 * 8);
  }

  f32x4 acc[8] = {};
  float m = -1e30f, lsum = 0.f;

  int ks0 = q0 - (WIN - 1); if (ks0 < 0) ks0 = 0;
  ks0 &= ~31;
  const int kend = q0 + 32;

  auto stage = [&](int b, int k0) {
    for (int c = 0; c < 2; ++c) {
      int base = w * 2048 + c * 1024;            // bytes in 8KB tile
      int idx = base / 16 + lane;                // 16B chunk index
      {
        int row = idx >> 4;                      // K row (32 rows x 256B)
        int col = (idx & 15) ^ (row & 7);
        gload16(Kb + ((size_t)kvh * T_SEQ + k0 + row) * DH + col * 8,
                (char*)kls[b] + base);
      }
      {
        int d = idx >> 2;                        // V^T row (128 rows x 64B)
        int ch = (idx & 3) ^ ((d >> 1) & 3);
        gload16(Vt + ((size_t)kvh * DH + d) * T_SEQ + k0 + ch * 8,
                (char*)vls[b] + base);
      }
    }
  };

  stage(0, ks0);
  int buf = 0;
  for (int k0 = ks0; k0 <= kend; k0 += 32) {
    bool more = (k0 + 32 <= kend);
    if (more) stage(buf ^ 1, k0 + 32);
    if (more) { WAITVM4(); } else { WAITVM0(); }
    __builtin_amdgcn_s_barrier();
    __builtin_amdgcn_sched_barrier(0);

    if (k0 <= wq0 + 15 && k0 + 31 >= wq0 - (WIN - 1)) {
      f32x4 st[2];
      for (int kh = 0; kh < 2; ++kh) {
        f32x4 s = {};
        int row = kh * 16 + l15;
        const char* kb = (const char*)kls[buf] + row * 256;
        for (int ks = 0; ks < 4; ++ks) {
          int chunk = (ks * 4 + l4) ^ (row & 7);
          bf16x8 kf = *(const bf16x8*)(kb + chunk * 16);
          s = __builtin_amdgcn_mfma_f32_16x16x32_bf16(kf, qf[ks], s, 0, 0, 0);
        }
        st[kh] = s;
      }
      const int q = wq0 + l15;
      float pv[2][4];
      float mx = -3e38f;
      for (int kh = 0; kh < 2; ++kh)
        for (int i = 0; i < 4; ++i) {
          int k = k0 + kh * 16 + l4 * 4 + i;
          bool ok = ((k >> 2) <= (q >> 2)) && (q - k < WIN);
          float s = ok ? st[kh][i] : -3e38f;
          pv[kh][i] = s;
          mx = fmaxf(mx, s);
        }
      mx = fmaxf(mx, __shfl_xor(mx, 16));
      mx = fmaxf(mx, __shfl_xor(mx, 32));
      if (!__all(mx <= m + 8.f)) {
        float mn = fmaxf(m, mx);
        float sc = __expf(m - mn);
        m = mn;
        lsum *= sc;
        for (int nt = 0; nt < 8; ++nt)
          for (int i = 0; i < 4; ++i) acc[nt][i] *= sc;
      }
      float rs = 0.f;
      for (int kh = 0; kh < 2; ++kh)
        for (int i = 0; i < 4; ++i) {
          float p = __expf(pv[kh][i] - m);
          pv[kh][i] = p;
          rs += p;
        }
      rs += __shfl_xor(rs, 16);
      rs += __shfl_xor(rs, 32);
      lsum += rs;
      u16* pw = plds[w];
      for (int kh = 0; kh < 2; ++kh) {
        unsigned int d0 = (unsigned int)f2bf(pv[kh][0]) | ((unsigned int)f2bf(pv[kh][1]) << 16);
        unsigned int d1 = (unsigned int)f2bf(pv[kh][2]) | ((unsigned int)f2bf(pv[kh][3]) << 16);
        *(unsigned int*)(pw + l15 * 40 + kh * 16 + l4 * 4) = d0;
        *(unsigned int*)(pw + l15 * 40 + kh * 16 + l4 * 4 + 2) = d1;
      }
      bf16x8 pf = *(const bf16x8*)(pw + l15 * 40 + l4 * 8);
      for (int nt = 0; nt < 8; ++nt) {
        int d = nt * 16 + l15;
        int chunk = l4 ^ ((d >> 1) & 3);
        bf16x8 vf = *(const bf16x8*)((const char*)vls[buf] + d * 64 + chunk * 16);
        acc[nt] = __builtin_amdgcn_mfma_f32_16x16x32_bf16(vf, pf, acc[nt], 0, 0, 0);
      }
    }
    __builtin_amdgcn_sched_barrier(0);
    __builtin_amdgcn_s_barrier();
    buf ^= 1;
  }

  float inv = 1.0f / lsum;
  for (int nt = 0; nt < 8; ++nt) {
    u16x4 o;
    for (int i = 0; i < 4; ++i) o[i] = f2bf(acc[nt][i] * inv);
    *(u16x4*)(O + (size_t)(wq0 + l15) * (NQ * DH) + h * DH + nt * 16 + l4 * 4) = o;
  }
}

extern "C" void kernel_launch(void* const* d_in, const int* in_sizes, int n_in,
                              void* d_out, int out_size, void* d_ws, size_t ws_size,
                              hipStream_t stream) {
  const float* hidden = (const float*)d_in[0];
  const float* cosb   = (const float*)d_in[1];
  const float* sinb   = (const float*)d_in[2];
  const float* w_qkv  = (const float*)d_in[3];
  const float* qnw    = (const float*)d_in[4];
  const float* knw    = (const float*)d_in[5];
  const float* w_o    = (const float*)d_in[6];
  float* out = (float*)d_out;
  char* ws = (char*)d_ws;

  u16*   wqkvT  = (u16*)(ws);                        // [0, 48M)
  u16*   hid_bf = (u16*)(ws + ((size_t)48 << 20));   // [48M, 64M)
  float* qkv    = (float*)(ws + ((size_t)64 << 20)); // [64M, 112M) (dead after rope)
  u16*   q_bf   = (u16*)(ws + ((size_t)112 << 20));  // 16MB
  u16*   k_bf   = (u16*)(ws + ((size_t)128 << 20));  // 4MB
  u16*   vt_bf  = (u16*)(ws + ((size_t)132 << 20));  // 4MB
  u16*   attn_bf= (u16*)(ws + ((size_t)48 << 20));   // reuse hid_bf region
  u16*   woT    = (u16*)(ws);                        // reuse wqkvT region
  float* part   = (float*)(ws + ((size_t)64 << 20)); // reuse qkv region (32MB)

  f32_to_bf16<<<4096, 256, 0, stream>>>(hidden, hid_bf, T_SEQ * HID);
  transpose_f32_to_bf16<<<dim3(192, 128), dim3(32, 8), 0, stream>>>(w_qkv, wqkvT, HID, 6144);
  // gemm1: 2048x6144x4096, grid 8x24=192, NT=64
  gemm8p<<<dim3(192, 1), 512, 0, stream>>>(hid_bf, wqkvT, qkv, qkv, 6144, HID, 64, 8);
  transpose_f32_to_bf16<<<dim3(128, 128), dim3(32, 8), 0, stream>>>(w_o, woT, NQ * DH, HID);
  rope_kernel<<<(T_SEQ * 48) / 4, 256, 0, stream>>>(qkv, cosb, sinb, qnw, knw, q_bf, k_bf, vt_bf);
  attn_kernel<<<dim3(NQ, T_SEQ / 64), 256, 0, stream>>>(q_bf, k_bf, vt_bf, attn_bf);
  // gemm2: 2048x4096x4096 split-K=2 (grid 8x16=128 per half, y = K-half), NT=32
  gemm8p<<<dim3(128, 2), 512, 0, stream>>>(attn_bf, woT, out, part, HID, NQ * DH, 32, 8);
  add_f32<<<T_SEQ * HID / 1024, 256, 0, stream>>>(out, part, T_SEQ * HID);
}

// Round 6
// 353.378 us; speedup vs baseline: 1.1375x; 1.1375x over previous
//
#include <hip/hip_runtime.h>
#include <hip/hip_bf16.h>

typedef unsigned short u16;
typedef __attribute__((ext_vector_type(8))) short bf16x8;
typedef __attribute__((ext_vector_type(4))) float f32x4;
typedef __attribute__((ext_vector_type(8))) u16 u16x8;
typedef __attribute__((ext_vector_type(4))) u16 u16x4;

#define T_SEQ 2048
#define HID 4096
#define NQ 32
#define NKV 8
#define DH 128
#define WIN 1024

__device__ __forceinline__ u16 f2bf(float f) {
  union { float f; unsigned int u; } v; v.f = f;
  unsigned int u = v.u;
  unsigned int r = (u + 0x7FFFu + ((u >> 16) & 1u)) >> 16;
  return (u16)r;
}

__device__ __forceinline__ void gload16(const void* g, void* l) {
  __builtin_amdgcn_global_load_lds(
      (const __attribute__((address_space(1))) unsigned int*)g,
      (__attribute__((address_space(3))) unsigned int*)l, 16, 0, 0);
}

// ---------------- elementwise f32 -> bf16 ----------------
__global__ __launch_bounds__(256) void f32_to_bf16(const float* __restrict__ in,
                                                   u16* __restrict__ out, int n) {
  int i = (blockIdx.x * 256 + threadIdx.x) * 8;
  if (i >= n) return;
  float4 a = *(const float4*)(in + i);
  float4 b = *(const float4*)(in + i + 4);
  u16x8 r;
  r[0] = f2bf(a.x); r[1] = f2bf(a.y); r[2] = f2bf(a.z); r[3] = f2bf(a.w);
  r[4] = f2bf(b.x); r[5] = f2bf(b.y); r[6] = f2bf(b.z); r[7] = f2bf(b.w);
  *(u16x8*)(out + i) = r;
}

// ---------------- tiled transpose f32 (R x C) -> bf16 (C x R) ----------------
__global__ __launch_bounds__(256) void transpose_f32_to_bf16(const float* __restrict__ in,
                                                             u16* __restrict__ out,
                                                             int R, int C) {
  __shared__ float tile[32][33];
  int c0 = blockIdx.x * 32, r0 = blockIdx.y * 32;
  int tx = threadIdx.x, ty = threadIdx.y;
  for (int i = 0; i < 32; i += 8)
    tile[ty + i][tx] = in[(size_t)(r0 + ty + i) * C + c0 + tx];
  __syncthreads();
  for (int i = 0; i < 32; i += 8)
    out[(size_t)(c0 + ty + i) * R + r0 + tx] = f2bf(tile[tx][ty + i]);
}

// ---------------- 256x192 8-phase GEMM (full-fill variant for gemm1) ----------------
// C(f32 2048x6144) = A(bf16 2048x4096 rm) * Bt(bf16 6144x4096 rm)^T
// Grid 8x32 = 256 blocks (exact chip fill). BM=256, BN=192, BK=64.
// 8 waves 4Mx2N (per-wave 64x96 = 4mf x 6nf); 4 phases/tile, quadrant =
// (mh: 2mf) x (nh: 3nf) = 12 MFMA. LDS 112KB: A 2x32KB, B 2x24KB.
// Stage units of 8KB (512 thr x 16B): A=4 units, B=3 units per tile.
// P1: rd afA+bfr0, stage A(t+1)u01 [slot^1]; P2: rd bfr1, stage A(t+1)u23;
// P3: rd afB, stage B(t+2)u01 [slot]; P4: stage B(t+2)u2, vmcnt(3).
// Hazards: B(t) reads done end-P2 (B(t+2) stages at P3+ OK); slot^1 A reads
// (tile t-1) done end-P3(t-1) (A(t+1) stages at P1(t) OK). vmcnt(3) at end-P4
// retires B(t+1)+A(t+1), leaves B(t+2) flying. Tail clamps (dummy reloads).
__global__ __launch_bounds__(512, 2) void gemm192(const u16* __restrict__ A,
                                                  const u16* __restrict__ Bt,
                                                  float* __restrict__ C,
                                                  int N, int K, int NT) {
  __shared__ u16 lsA[2][16384];   // [slot][256*64]
  __shared__ u16 lsB[2][12288];   // [slot][192*64]
  const int tid = threadIdx.x;
  const int lane = tid & 63, w = tid >> 6;
  const int wm = w >> 1, wn = w & 1;          // 4M x 2N
  const int l15 = lane & 15, l4 = lane >> 4;

  const int nwg = gridDim.x;
  const int cpx = nwg >> 3;
  const int bid = blockIdx.x;
  const int swz = (bid & 7) * cpx + (bid >> 3);
  const int bm = (swz & 7) * 256;
  const int bn = (swz >> 3) * 192;

  auto stageA = [&](int unit, int slot, int kt) {
    int r = tid >> 3, cp = tid & 7;
    int scp = cp ^ (r & 7);
    gload16(A + (size_t)(bm + unit * 64 + r) * K + kt * 64 + scp * 8,
            (char*)lsA[slot] + (unit * 512 + tid) * 16);
  };
  auto stageB = [&](int unit, int slot, int kt) {
    int r = tid >> 3, cp = tid & 7;
    int scp = cp ^ (r & 7);
    gload16(Bt + (size_t)(bn + unit * 64 + r) * K + kt * 64 + scp * 8,
            (char*)lsB[slot] + (unit * 512 + tid) * 16);
  };
  auto rdA = [&](int slot, int mh, int mf, int ks) -> bf16x8 {
    int r = wm * 64 + mh * 32 + mf * 16 + l15;
    int ch = (ks * 4 + l4) ^ (r & 7);
    return *(const bf16x8*)(lsA[slot] + r * 64 + ch * 8);
  };
  auto rdB = [&](int slot, int nh, int nf, int ks) -> bf16x8 {
    int r = wn * 96 + nh * 48 + nf * 16 + l15;
    int ch = (ks * 4 + l4) ^ (r & 7);
    return *(const bf16x8*)(lsB[slot] + r * 64 + ch * 8);
  };

  f32x4 acc[4][6] = {};
  bf16x8 afA[2][2], afB[2][2], bfr0[3][2], bfr1[3][2];

  // prologue: A(0) 4u + B(0) 3u + B(1) 3u; vmcnt(3) -> tile0 resident
  stageA(0, 0, 0); stageA(1, 0, 0); stageA(2, 0, 0); stageA(3, 0, 0);
  stageB(0, 0, 0); stageB(1, 0, 0); stageB(2, 0, 0);
  stageB(0, 1, 1); stageB(1, 1, 1); stageB(2, 1, 1);
  asm volatile("s_waitcnt vmcnt(3)" ::: "memory");
  __builtin_amdgcn_s_barrier();

  for (int t = 0; t < NT; ++t) {
    const int s = t & 1;
    const int ktA = (t + 1 < NT) ? t + 1 : NT - 1;
    const int ktB = (t + 2 < NT) ? t + 2 : NT - 1;

    // ---- P1: rd afA+bfr0; stage A(t+1)u0,u1; MFMA (mh0,nh0) ----
#pragma unroll
    for (int mf = 0; mf < 2; ++mf)
#pragma unroll
      for (int ks = 0; ks < 2; ++ks) afA[mf][ks] = rdA(s, 0, mf, ks);
#pragma unroll
    for (int nf = 0; nf < 3; ++nf)
#pragma unroll
      for (int ks = 0; ks < 2; ++ks) bfr0[nf][ks] = rdB(s, 0, nf, ks);
    stageA(0, s ^ 1, ktA); stageA(1, s ^ 1, ktA);
    __builtin_amdgcn_s_barrier();
    asm volatile("s_waitcnt lgkmcnt(0)" ::: "memory");
    __builtin_amdgcn_sched_barrier(0);
    __builtin_amdgcn_s_setprio(1);
#pragma unroll
    for (int mf = 0; mf < 2; ++mf)
#pragma unroll
      for (int nf = 0; nf < 3; ++nf) {
        acc[mf][nf] = __builtin_amdgcn_mfma_f32_16x16x32_bf16(afA[mf][0], bfr0[nf][0], acc[mf][nf], 0, 0, 0);
        acc[mf][nf] = __builtin_amdgcn_mfma_f32_16x16x32_bf16(afA[mf][1], bfr0[nf][1], acc[mf][nf], 0, 0, 0);
      }
    __builtin_amdgcn_s_setprio(0);
    __builtin_amdgcn_s_barrier();

    // ---- P2: rd bfr1; stage A(t+1)u2,u3; MFMA (mh0,nh1) ----
#pragma unroll
    for (int nf = 0; nf < 3; ++nf)
#pragma unroll
      for (int ks = 0; ks < 2; ++ks) bfr1[nf][ks] = rdB(s, 1, nf, ks);
    stageA(2, s ^ 1, ktA); stageA(3, s ^ 1, ktA);
    __builtin_amdgcn_s_barrier();
    asm volatile("s_waitcnt lgkmcnt(0)" ::: "memory");
    __builtin_amdgcn_sched_barrier(0);
    __builtin_amdgcn_s_setprio(1);
#pragma unroll
    for (int mf = 0; mf < 2; ++mf)
#pragma unroll
      for (int nf = 0; nf < 3; ++nf) {
        acc[mf][3 + nf] = __builtin_amdgcn_mfma_f32_16x16x32_bf16(afA[mf][0], bfr1[nf][0], acc[mf][3 + nf], 0, 0, 0);
        acc[mf][3 + nf] = __builtin_amdgcn_mfma_f32_16x16x32_bf16(afA[mf][1], bfr1[nf][1], acc[mf][3 + nf], 0, 0, 0);
      }
    __builtin_amdgcn_s_setprio(0);
    __builtin_amdgcn_s_barrier();

    // ---- P3: rd afB; stage B(t+2)u0,u1; MFMA (mh1,nh0) ----
#pragma unroll
    for (int mf = 0; mf < 2; ++mf)
#pragma unroll
      for (int ks = 0; ks < 2; ++ks) afB[mf][ks] = rdA(s, 1, mf, ks);
    stageB(0, s, ktB); stageB(1, s, ktB);
    __builtin_amdgcn_s_barrier();
    asm volatile("s_waitcnt lgkmcnt(0)" ::: "memory");
    __builtin_amdgcn_sched_barrier(0);
    __builtin_amdgcn_s_setprio(1);
#pragma unroll
    for (int mf = 0; mf < 2; ++mf)
#pragma unroll
      for (int nf = 0; nf < 3; ++nf) {
        acc[2 + mf][nf] = __builtin_amdgcn_mfma_f32_16x16x32_bf16(afB[mf][0], bfr0[nf][0], acc[2 + mf][nf], 0, 0, 0);
        acc[2 + mf][nf] = __builtin_amdgcn_mfma_f32_16x16x32_bf16(afB[mf][1], bfr0[nf][1], acc[2 + mf][nf], 0, 0, 0);
      }
    __builtin_amdgcn_s_setprio(0);
    __builtin_amdgcn_s_barrier();

    // ---- P4: stage B(t+2)u2; MFMA (mh1,nh1); vmcnt(3) ----
    stageB(2, s, ktB);
    __builtin_amdgcn_s_barrier();
    __builtin_amdgcn_s_setprio(1);
#pragma unroll
    for (int mf = 0; mf < 2; ++mf)
#pragma unroll
      for (int nf = 0; nf < 3; ++nf) {
        acc[2 + mf][3 + nf] = __builtin_amdgcn_mfma_f32_16x16x32_bf16(afB[mf][0], bfr1[nf][0], acc[2 + mf][3 + nf], 0, 0, 0);
        acc[2 + mf][3 + nf] = __builtin_amdgcn_mfma_f32_16x16x32_bf16(afB[mf][1], bfr1[nf][1], acc[2 + mf][3 + nf], 0, 0, 0);
      }
    __builtin_amdgcn_s_setprio(0);
    asm volatile("s_waitcnt vmcnt(3)" ::: "memory");   // A(t+1)+B(t+1) resident
    __builtin_amdgcn_s_barrier();
  }

  asm volatile("s_waitcnt vmcnt(0)" ::: "memory");     // drain tail dummies

#pragma unroll
  for (int mi = 0; mi < 4; ++mi)
#pragma unroll
    for (int ni = 0; ni < 6; ++ni) {
      int row = bm + wm * 64 + mi * 16 + l4 * 4;
      int col = bn + wn * 96 + ni * 16 + l15;
      float* p = C + (size_t)row * N + col;
      p[0] = acc[mi][ni][0];
      p[(size_t)N] = acc[mi][ni][1];
      p[2 * (size_t)N] = acc[mi][ni][2];
      p[3 * (size_t)N] = acc[mi][ni][3];
    }
}

// ---------------- 256x256 8-phase GEMM (R3 schedule, used for gemm2 split-K) ----------------
// C(f32 MxN) = A(bf16 MxK rm) * Bt(bf16 NxK rm)^T, K-slice [kt0*64, (kt0+NT)*64)
// BK=64, 2-buf LDS (128KB), 8 waves 2Mx4N (per-wave 128x64).
// Per tile: 4 phases {ds_read quadrant | stage 1 half-tile -> barrier ->
// lgkmcnt(0) -> setprio+16 MFMA -> barrier}; vmcnt(4) once per tile at end-P4.
// Stage stream: P1->A0(t+1), P2->A1(t+1) [buf^1], P3->B0(t+2), P4->B1(t+2) [buf].
__global__ __launch_bounds__(512, 2) void gemm8p(const u16* __restrict__ A,
                                                 const u16* __restrict__ Bt,
                                                 float* __restrict__ C,
                                                 float* __restrict__ Cp,
                                                 int N, int K, int NT, int MT) {
  __shared__ u16 lsA[2][2][8192];   // [buf][half][128*64]
  __shared__ u16 lsB[2][2][8192];
  const int tid = threadIdx.x;
  const int lane = tid & 63, w = tid >> 6;
  const int wm = w >> 2, wn = w & 3;
  const int l15 = lane & 15, l4 = lane >> 4;

  const int nwg = gridDim.x;
  const int cpx = nwg >> 3;
  const int bid = blockIdx.x;
  const int swz = (bid & 7) * cpx + (bid >> 3);
  const int bm = (swz % MT) * 256;
  const int bn = (swz / MT) * 256;
  const int kt0 = blockIdx.y * NT;
  float* __restrict__ dst = blockIdx.y ? Cp : C;

  auto stageH = [&](int mat, int half, int buf, int kt) {
    const u16* src = mat ? Bt : A;
    int base_row = (mat ? bn : bm) + half * 128;
    u16* d = mat ? lsB[buf][half] : lsA[buf][half];
#pragma unroll
    for (int c = 0; c < 2; ++c) {
      int ci = (w * 2 + c) * 64 + lane;     // 16B chunk 0..1023
      int r = ci >> 3, cp = ci & 7;
      int scp = cp ^ (r & 7);               // pre-swizzled source chunk
      gload16(src + (size_t)(base_row + r) * K + kt * 64 + scp * 8,
              (char*)d + (w * 2 + c) * 1024);
    }
  };
  auto rdA = [&](int buf, int mh, int fr, int ks) -> bf16x8 {
    int r = mh * 64 + fr * 16 + l15;
    int ch = (ks * 4 + l4) ^ (r & 7);
    return *(const bf16x8*)(lsA[buf][wm] + r * 64 + ch * 8);
  };
  auto rdB = [&](int buf, int nh, int g, int ks) -> bf16x8 {
    int r = (wn * 64 + nh * 32 + g * 16 + l15) & 127;
    int ch = (ks * 4 + l4) ^ (r & 7);
    return *(const bf16x8*)(lsB[buf][wn >> 1] + r * 64 + ch * 8);
  };

  f32x4 acc[8][4] = {};
  bf16x8 af[4][2], bfr[2][2][2];

  // prologue: tile0 all 4 halves + tile1 B-halves (12 loads)
  stageH(0, 0, 0, kt0);     stageH(0, 1, 0, kt0);
  stageH(1, 0, 0, kt0);     stageH(1, 1, 0, kt0);
  stageH(1, 0, 1, kt0 + 1); stageH(1, 1, 1, kt0 + 1);
  asm volatile("s_waitcnt vmcnt(4)" ::: "memory");   // tile0 resident
  __builtin_amdgcn_s_barrier();

  for (int t = 0; t < NT; ++t) {
    const int b = t & 1;
    const int tA = kt0 + ((t + 1 < NT) ? t + 1 : NT - 1);
    const int tB = kt0 + ((t + 2 < NT) ? t + 2 : NT - 1);

    // ---- P1: Q(mh0,nh0) ----
#pragma unroll
    for (int fr = 0; fr < 4; ++fr)
#pragma unroll
      for (int ks = 0; ks < 2; ++ks) af[fr][ks] = rdA(b, 0, fr, ks);
#pragma unroll
    for (int g = 0; g < 2; ++g)
#pragma unroll
      for (int ks = 0; ks < 2; ++ks) bfr[0][g][ks] = rdB(b, 0, g, ks);
    stageH(0, 0, b ^ 1, tA);
    __builtin_amdgcn_s_barrier();
    asm volatile("s_waitcnt lgkmcnt(0)" ::: "memory");
    __builtin_amdgcn_sched_barrier(0);
    __builtin_amdgcn_s_setprio(1);
#pragma unroll
    for (int fr = 0; fr < 4; ++fr)
#pragma unroll
      for (int g = 0; g < 2; ++g) {
        acc[fr][g] = __builtin_amdgcn_mfma_f32_16x16x32_bf16(af[fr][0], bfr[0][g][0], acc[fr][g], 0, 0, 0);
        acc[fr][g] = __builtin_amdgcn_mfma_f32_16x16x32_bf16(af[fr][1], bfr[0][g][1], acc[fr][g], 0, 0, 0);
      }
    __builtin_amdgcn_s_setprio(0);
    __builtin_amdgcn_s_barrier();

    // ---- P2: Q(mh0,nh1) ----
#pragma unroll
    for (int g = 0; g < 2; ++g)
#pragma unroll
      for (int ks = 0; ks < 2; ++ks) bfr[1][g][ks] = rdB(b, 1, g, ks);
    stageH(0, 1, b ^ 1, tA);
    __builtin_amdgcn_s_barrier();
    asm volatile("s_waitcnt lgkmcnt(0)" ::: "memory");
    __builtin_amdgcn_sched_barrier(0);
    __builtin_amdgcn_s_setprio(1);
#pragma unroll
    for (int fr = 0; fr < 4; ++fr)
#pragma unroll
      for (int g = 0; g < 2; ++g) {
        acc[fr][2 + g] = __builtin_amdgcn_mfma_f32_16x16x32_bf16(af[fr][0], bfr[1][g][0], acc[fr][2 + g], 0, 0, 0);
        acc[fr][2 + g] = __builtin_amdgcn_mfma_f32_16x16x32_bf16(af[fr][1], bfr[1][g][1], acc[fr][2 + g], 0, 0, 0);
      }
    __builtin_amdgcn_s_setprio(0);
    __builtin_amdgcn_s_barrier();

    // ---- P3: Q(mh1,nh0) ----
#pragma unroll
    for (int fr = 0; fr < 4; ++fr)
#pragma unroll
      for (int ks = 0; ks < 2; ++ks) af[fr][ks] = rdA(b, 1, fr, ks);
    stageH(1, 0, b, tB);
    __builtin_amdgcn_s_barrier();
    asm volatile("s_waitcnt lgkmcnt(0)" ::: "memory");
    __builtin_amdgcn_sched_barrier(0);
    __builtin_amdgcn_s_setprio(1);
#pragma unroll
    for (int fr = 0; fr < 4; ++fr)
#pragma unroll
      for (int g = 0; g < 2; ++g) {
        acc[4 + fr][g] = __builtin_amdgcn_mfma_f32_16x16x32_bf16(af[fr][0], bfr[0][g][0], acc[4 + fr][g], 0, 0, 0);
        acc[4 + fr][g] = __builtin_amdgcn_mfma_f32_16x16x32_bf16(af[fr][1], bfr[0][g][1], acc[4 + fr][g], 0, 0, 0);
      }
    __builtin_amdgcn_s_setprio(0);
    __builtin_amdgcn_s_barrier();

    // ---- P4: Q(mh1,nh1), no ds_reads ----
    stageH(1, 1, b, tB);
    __builtin_amdgcn_s_barrier();
    __builtin_amdgcn_s_setprio(1);
#pragma unroll
    for (int fr = 0; fr < 4; ++fr)
#pragma unroll
      for (int g = 0; g < 2; ++g) {
        acc[4 + fr][2 + g] = __builtin_amdgcn_mfma_f32_16x16x32_bf16(af[fr][0], bfr[1][g][0], acc[4 + fr][2 + g], 0, 0, 0);
        acc[4 + fr][2 + g] = __builtin_amdgcn_mfma_f32_16x16x32_bf16(af[fr][1], bfr[1][g][1], acc[4 + fr][2 + g], 0, 0, 0);
      }
    __builtin_amdgcn_s_setprio(0);
    asm volatile("s_waitcnt vmcnt(4)" ::: "memory");   // tile t+1 resident
    __builtin_amdgcn_s_barrier();
  }

  asm volatile("s_waitcnt vmcnt(0)" ::: "memory");     // drain tail dummies

#pragma unroll
  for (int mf = 0; mf < 8; ++mf)
#pragma unroll
    for (int nf = 0; nf < 4; ++nf) {
      int row = bm + wm * 128 + mf * 16 + l4 * 4;
      int col = bn + wn * 64 + nf * 16 + l15;
      float* p = dst + (size_t)row * N + col;
      p[0] = acc[mf][nf][0];
      p[(size_t)N] = acc[mf][nf][1];
      p[2 * (size_t)N] = acc[mf][nf][2];
      p[3 * (size_t)N] = acc[mf][nf][3];
    }
}

// ---------------- split-K reduce: c += p ----------------
__global__ __launch_bounds__(256) void add_f32(float* __restrict__ c,
                                               const float* __restrict__ p, int n) {
  int i = (blockIdx.x * 256 + threadIdx.x) * 4;
  if (i >= n) return;
  float4 a = *(float4*)(c + i);
  float4 b = *(const float4*)(p + i);
  a.x += b.x; a.y += b.y; a.z += b.z; a.w += b.w;
  *(float4*)(c + i) = a;
}

// ---------------- RMSNorm + RoPE + layout (Q scaled; Q,K row-major per head; V transposed) -------
__global__ __launch_bounds__(256) void rope_kernel(const float* __restrict__ qkv,
                                                   const float* __restrict__ cosb,
                                                   const float* __restrict__ sinb,
                                                   const float* __restrict__ qw,
                                                   const float* __restrict__ kw,
                                                   u16* __restrict__ Qo,
                                                   u16* __restrict__ Ko,
                                                   u16* __restrict__ Vt) {
  int wid = threadIdx.x >> 6, lane = threadIdx.x & 63;
  int item = blockIdx.x * 4 + wid;          // item = t*48 + hid
  int t = item / 48, hid = item % 48;
  const float* x = qkv + (size_t)t * 6144 + hid * 128;
  float x1 = x[lane], x2 = x[lane + 64];
  if (hid < NQ + NKV) {
    float ss = x1 * x1 + x2 * x2;
    for (int off = 32; off; off >>= 1) ss += __shfl_xor(ss, off);
    float inv = rsqrtf(ss * (1.0f / 128.0f) + 1e-6f);
    const float* wn = (hid < NQ) ? qw : kw;
    float n1 = x1 * inv * wn[lane], n2 = x2 * inv * wn[lane + 64];
    float c1 = cosb[t * 128 + lane], s1 = sinb[t * 128 + lane];
    float c2 = cosb[t * 128 + lane + 64], s2 = sinb[t * 128 + lane + 64];
    float o1 = n1 * c1 - n2 * s1;
    float o2 = n2 * c2 + n1 * s2;
    if (hid < NQ) {
      const float scale = 0.08838834764831845f;  // fold 1/sqrt(128) into Q
      u16* q = Qo + ((size_t)hid * T_SEQ + t) * 128;
      q[lane] = f2bf(o1 * scale); q[lane + 64] = f2bf(o2 * scale);
    } else {
      int h = hid - NQ;
      u16* k = Ko + ((size_t)h * T_SEQ + t) * 128;
      k[lane] = f2bf(o1); k[lane + 64] = f2bf(o2);
    }
  } else {
    int h = hid - (NQ + NKV);
    Vt[((size_t)h * 128 + lane) * T_SEQ + t] = f2bf(x1);
    Vt[((size_t)h * 128 + lane + 64) * T_SEQ + t] = f2bf(x2);
  }
}

#define WAITVM4() asm volatile("s_waitcnt vmcnt(4)" ::: "memory")
#define WAITVM0() asm volatile("s_waitcnt vmcnt(0)" ::: "memory")

// ---------------- flash attention: 4 waves/block, QBLK=64, KBLK=32, LDS dbuf ----------------
__global__ __launch_bounds__(256) void attn_kernel(const u16* __restrict__ Q,
                                                   const u16* __restrict__ Kb,
                                                   const u16* __restrict__ Vt,
                                                   u16* __restrict__ O) {
  __shared__ u16 kls[2][32 * 128];   // swizzled: chunk16 ^= (row&7)
  __shared__ u16 vls[2][128 * 32];   // swizzled: chunk16 ^= ((d>>1)&3)
  __shared__ u16 plds[4][16 * 40];   // per-wave P buffer [16 q][32 k] pad to 40

  const int tid = threadIdx.x;
  const int lane = tid & 63, w = tid >> 6;
  const int l15 = lane & 15, l4 = lane >> 4;
  const int h = blockIdx.x;          // q head
  const int q0 = blockIdx.y * 64;    // block q base
  const int wq0 = q0 + w * 16;       // wave q base
  const int kvh = h >> 2;

  bf16x8 qf[4];
  {
    const u16* qrow = Q + ((size_t)h * T_SEQ + (wq0 + l15)) * DH;
    for (int ks = 0; ks < 4; ++ks)
      qf[ks] = *(const bf16x8*)(qrow + ks * 32 + l4 * 8);
  }

  f32x4 acc[8] = {};
  float m = -1e30f, lsum = 0.f;

  int ks0 = q0 - (WIN - 1); if (ks0 < 0) ks0 = 0;
  ks0 &= ~31;
  const int kend = q0 + 32;

  auto stage = [&](int b, int k0) {
    for (int c = 0; c < 2; ++c) {
      int base = w * 2048 + c * 1024;            // bytes in 8KB tile
      int idx = base / 16 + lane;                // 16B chunk index
      {
        int row = idx >> 4;                      // K row (32 rows x 256B)
        int col = (idx & 15) ^ (row & 7);
        gload16(Kb + ((size_t)kvh * T_SEQ + k0 + row) * DH + col * 8,
                (char*)kls[b] + base);
      }
      {
        int d = idx >> 2;                        // V^T row (128 rows x 64B)
        int ch = (idx & 3) ^ ((d >> 1) & 3);
        gload16(Vt + ((size_t)kvh * DH + d) * T_SEQ + k0 + ch * 8,
                (char*)vls[b] + base);
      }
    }
  };

  stage(0, ks0);
  int buf = 0;
  for (int k0 = ks0; k0 <= kend; k0 += 32) {
    bool more = (k0 + 32 <= kend);
    if (more) stage(buf ^ 1, k0 + 32);
    if (more) { WAITVM4(); } else { WAITVM0(); }
    __builtin_amdgcn_s_barrier();
    __builtin_amdgcn_sched_barrier(0);

    if (k0 <= wq0 + 15 && k0 + 31 >= wq0 - (WIN - 1)) {
      f32x4 st[2];
      for (int kh = 0; kh < 2; ++kh) {
        f32x4 s = {};
        int row = kh * 16 + l15;
        const char* kb = (const char*)kls[buf] + row * 256;
        for (int ks = 0; ks < 4; ++ks) {
          int chunk = (ks * 4 + l4) ^ (row & 7);
          bf16x8 kf = *(const bf16x8*)(kb + chunk * 16);
          s = __builtin_amdgcn_mfma_f32_16x16x32_bf16(kf, qf[ks], s, 0, 0, 0);
        }
        st[kh] = s;
      }
      const int q = wq0 + l15;
      float pv[2][4];
      float mx = -3e38f;
      for (int kh = 0; kh < 2; ++kh)
        for (int i = 0; i < 4; ++i) {
          int k = k0 + kh * 16 + l4 * 4 + i;
          bool ok = ((k >> 2) <= (q >> 2)) && (q - k < WIN);
          float s = ok ? st[kh][i] : -3e38f;
          pv[kh][i] = s;
          mx = fmaxf(mx, s);
        }
      mx = fmaxf(mx, __shfl_xor(mx, 16));
      mx = fmaxf(mx, __shfl_xor(mx, 32));
      if (!__all(mx <= m + 8.f)) {
        float mn = fmaxf(m, mx);
        float sc = __expf(m - mn);
        m = mn;
        lsum *= sc;
        for (int nt = 0; nt < 8; ++nt)
          for (int i = 0; i < 4; ++i) acc[nt][i] *= sc;
      }
      float rs = 0.f;
      for (int kh = 0; kh < 2; ++kh)
        for (int i = 0; i < 4; ++i) {
          float p = __expf(pv[kh][i] - m);
          pv[kh][i] = p;
          rs += p;
        }
      rs += __shfl_xor(rs, 16);
      rs += __shfl_xor(rs, 32);
      lsum += rs;
      u16* pw = plds[w];
      for (int kh = 0; kh < 2; ++kh) {
        unsigned int d0 = (unsigned int)f2bf(pv[kh][0]) | ((unsigned int)f2bf(pv[kh][1]) << 16);
        unsigned int d1 = (unsigned int)f2bf(pv[kh][2]) | ((unsigned int)f2bf(pv[kh][3]) << 16);
        *(unsigned int*)(pw + l15 * 40 + kh * 16 + l4 * 4) = d0;
        *(unsigned int*)(pw + l15 * 40 + kh * 16 + l4 * 4 + 2) = d1;
      }
      bf16x8 pf = *(const bf16x8*)(pw + l15 * 40 + l4 * 8);
      for (int nt = 0; nt < 8; ++nt) {
        int d = nt * 16 + l15;
        int chunk = l4 ^ ((d >> 1) & 3);
        bf16x8 vf = *(const bf16x8*)((const char*)vls[buf] + d * 64 + chunk * 16);
        acc[nt] = __builtin_amdgcn_mfma_f32_16x16x32_bf16(vf, pf, acc[nt], 0, 0, 0);
      }
    }
    __builtin_amdgcn_sched_barrier(0);
    __builtin_amdgcn_s_barrier();
    buf ^= 1;
  }

  float inv = 1.0f / lsum;
  for (int nt = 0; nt < 8; ++nt) {
    u16x4 o;
    for (int i = 0; i < 4; ++i) o[i] = f2bf(acc[nt][i] * inv);
    *(u16x4*)(O + (size_t)(wq0 + l15) * (NQ * DH) + h * DH + nt * 16 + l4 * 4) = o;
  }
}

extern "C" void kernel_launch(void* const* d_in, const int* in_sizes, int n_in,
                              void* d_out, int out_size, void* d_ws, size_t ws_size,
                              hipStream_t stream) {
  const float* hidden = (const float*)d_in[0];
  const float* cosb   = (const float*)d_in[1];
  const float* sinb   = (const float*)d_in[2];
  const float* w_qkv  = (const float*)d_in[3];
  const float* qnw    = (const float*)d_in[4];
  const float* knw    = (const float*)d_in[5];
  const float* w_o    = (const float*)d_in[6];
  float* out = (float*)d_out;
  char* ws = (char*)d_ws;

  u16*   wqkvT  = (u16*)(ws);                        // [0, 48M)
  u16*   hid_bf = (u16*)(ws + ((size_t)48 << 20));   // [48M, 64M)
  float* qkv    = (float*)(ws + ((size_t)64 << 20)); // [64M, 112M) (dead after rope)
  u16*   q_bf   = (u16*)(ws + ((size_t)112 << 20));  // 16MB
  u16*   k_bf   = (u16*)(ws + ((size_t)128 << 20));  // 4MB
  u16*   vt_bf  = (u16*)(ws + ((size_t)132 << 20));  // 4MB
  u16*   attn_bf= (u16*)(ws + ((size_t)48 << 20));   // reuse hid_bf region
  u16*   woT    = (u16*)(ws);                        // reuse wqkvT region
  float* part   = (float*)(ws + ((size_t)64 << 20)); // reuse qkv region (32MB)

  f32_to_bf16<<<4096, 256, 0, stream>>>(hidden, hid_bf, T_SEQ * HID);
  transpose_f32_to_bf16<<<dim3(192, 128), dim3(32, 8), 0, stream>>>(w_qkv, wqkvT, HID, 6144);
  // gemm1: 2048x6144x4096, BN=192 -> grid 8x32 = 256 blocks (full fill), NT=64
  gemm192<<<256, 512, 0, stream>>>(hid_bf, wqkvT, qkv, 6144, HID, 64);
  transpose_f32_to_bf16<<<dim3(128, 128), dim3(32, 8), 0, stream>>>(w_o, woT, NQ * DH, HID);
  rope_kernel<<<(T_SEQ * 48) / 4, 256, 0, stream>>>(qkv, cosb, sinb, qnw, knw, q_bf, k_bf, vt_bf);
  attn_kernel<<<dim3(NQ, T_SEQ / 64), 256, 0, stream>>>(q_bf, k_bf, vt_bf, attn_bf);
  // gemm2: 2048x4096x4096 split-K=2 (grid 8x16=128 per half, y = K-half), NT=32
  gemm8p<<<dim3(128, 2), 512, 0, stream>>>(attn_bf, woT, out, part, HID, NQ * DH, 32, 8);
  add_f32<<<T_SEQ * HID / 1024, 256, 0, stream>>>(out, part, T_SEQ * HID);
}

// Round 7
// 344.965 us; speedup vs baseline: 1.1653x; 1.0244x over previous
//
#include <hip/hip_runtime.h>
#include <hip/hip_bf16.h>

typedef unsigned short u16;
typedef __attribute__((ext_vector_type(8))) short bf16x8;
typedef __attribute__((ext_vector_type(4))) float f32x4;
typedef __attribute__((ext_vector_type(8))) u16 u16x8;
typedef __attribute__((ext_vector_type(4))) u16 u16x4;

#define T_SEQ 2048
#define HID 4096
#define NQ 32
#define NKV 8
#define DH 128
#define WIN 1024

__device__ __forceinline__ u16 f2bf(float f) {
  union { float f; unsigned int u; } v; v.f = f;
  unsigned int u = v.u;
  unsigned int r = (u + 0x7FFFu + ((u >> 16) & 1u)) >> 16;
  return (u16)r;
}
__device__ __forceinline__ float bf2f(u16 b) {
  union { unsigned int u; float f; } v; v.u = ((unsigned int)b) << 16;
  return v.f;
}

__device__ __forceinline__ void gload16(const void* g, void* l) {
  __builtin_amdgcn_global_load_lds(
      (const __attribute__((address_space(1))) unsigned int*)g,
      (__attribute__((address_space(3))) unsigned int*)l, 16, 0, 0);
}

// ---------------- elementwise f32 -> bf16 ----------------
__global__ __launch_bounds__(256) void f32_to_bf16(const float* __restrict__ in,
                                                   u16* __restrict__ out, int n) {
  int i = (blockIdx.x * 256 + threadIdx.x) * 8;
  if (i >= n) return;
  float4 a = *(const float4*)(in + i);
  float4 b = *(const float4*)(in + i + 4);
  u16x8 r;
  r[0] = f2bf(a.x); r[1] = f2bf(a.y); r[2] = f2bf(a.z); r[3] = f2bf(a.w);
  r[4] = f2bf(b.x); r[5] = f2bf(b.y); r[6] = f2bf(b.z); r[7] = f2bf(b.w);
  *(u16x8*)(out + i) = r;
}

// ---------------- tiled transpose f32 (R x C) -> bf16 (C x R) ----------------
__global__ __launch_bounds__(256) void transpose_f32_to_bf16(const float* __restrict__ in,
                                                             u16* __restrict__ out,
                                                             int R, int C) {
  __shared__ float tile[32][33];
  int c0 = blockIdx.x * 32, r0 = blockIdx.y * 32;
  int tx = threadIdx.x, ty = threadIdx.y;
  for (int i = 0; i < 32; i += 8)
    tile[ty + i][tx] = in[(size_t)(r0 + ty + i) * C + c0 + tx];
  __syncthreads();
  for (int i = 0; i < 32; i += 8)
    out[(size_t)(c0 + ty + i) * R + r0 + tx] = f2bf(tile[tx][ty + i]);
}

// ---------------- 256xBN 4-phase full-fill GEMM (R5-proven schedule) ----------------
// C(MxN) = A(bf16 MxK rm) * Bt(bf16 NxK rm)^T.  BM=256, BN=NF*64, BK=64.
// Grid must be (M/256)*(N/BN) with x-major = M tiles (swz&7), and % 8 == 0.
// 8 waves 4Mx2N (per-wave 64 x NF*16*... ); 4 phases/tile, quadrant =
// (mh: 2mf) x (nh: NF nf).  LDS: A 2x32KB, B 2x(BN*128B).
// Stage units of 8KB (512 thr x 16B): A=4/tile, B=NB=BN/64 per tile.
// P1: rd afA+bfr0, stage A(t+1)u01 [slot^1]; P2: rd bfr1, stage A(t+1)u23;
// P3: rd afB, stage B(t+2) units 0..NB-2 [slot]; P4: stage B(t+2) last unit,
// vmcnt(NB) -> A(t+1)+B(t+1) resident, B(t+2) still flying.
// Hazards: B(t) reads done end-P2 (B(t+2) stages P3+ OK); slot^1 A reads
// (tile t-1) done end-P3(t-1) (A(t+1) stages P1(t) OK). Tail clamps (dummies).
// Swizzle chunk ^= row&7, pre-swizzled global source (both-sides involution).
template <int NF, bool BF16OUT>
__global__ __launch_bounds__(512, 2) void gemm_np(const u16* __restrict__ A,
                                                  const u16* __restrict__ Bt,
                                                  void* __restrict__ Cv,
                                                  int N, int K, int NT) {
  constexpr int HN = NF * 16;       // per-wave half-N (nh span)
  constexpr int BN = 4 * HN;        // block N
  constexpr int NB = BN / 64;       // B stage units per tile
  __shared__ u16 lsA[2][16384];     // [slot][256*64]
  __shared__ u16 lsB[2][BN * 64];
  const int tid = threadIdx.x;
  const int lane = tid & 63, w = tid >> 6;
  const int wm = w >> 1, wn = w & 1;          // 4M x 2N
  const int l15 = lane & 15, l4 = lane >> 4;

  const int nwg = gridDim.x;
  const int cpx = nwg >> 3;
  const int bid = blockIdx.x;
  const int swz = (bid & 7) * cpx + (bid >> 3);
  const int bm = (swz & 7) * 256;
  const int bn = (swz >> 3) * BN;

  auto stageA = [&](int unit, int slot, int kt) {
    int r = tid >> 3, cp = tid & 7;
    int scp = cp ^ (r & 7);
    gload16(A + (size_t)(bm + unit * 64 + r) * K + kt * 64 + scp * 8,
            (char*)lsA[slot] + (unit * 512 + tid) * 16);
  };
  auto stageB = [&](int unit, int slot, int kt) {
    int r = tid >> 3, cp = tid & 7;
    int scp = cp ^ (r & 7);
    gload16(Bt + (size_t)(bn + unit * 64 + r) * K + kt * 64 + scp * 8,
            (char*)lsB[slot] + (unit * 512 + tid) * 16);
  };
  auto rdA = [&](int slot, int mh, int mf, int ks) -> bf16x8 {
    int r = wm * 64 + mh * 32 + mf * 16 + l15;
    int ch = (ks * 4 + l4) ^ (r & 7);
    return *(const bf16x8*)(lsA[slot] + r * 64 + ch * 8);
  };
  auto rdB = [&](int slot, int nh, int nf, int ks) -> bf16x8 {
    int r = wn * 2 * HN + nh * HN + nf * 16 + l15;
    int ch = (ks * 4 + l4) ^ (r & 7);
    return *(const bf16x8*)(lsB[slot] + r * 64 + ch * 8);
  };

#define WAIT_NB() do { if constexpr (NB == 3) asm volatile("s_waitcnt vmcnt(3)" ::: "memory"); \
                       else                   asm volatile("s_waitcnt vmcnt(2)" ::: "memory"); } while (0)

  f32x4 acc[4][2 * NF] = {};
  bf16x8 afA[2][2], afB[2][2], bfr0[NF][2], bfr1[NF][2];

  // prologue: A(0) 4u + B(0) NBu + B(1) NBu; vmcnt(NB) -> tile0 resident
  stageA(0, 0, 0); stageA(1, 0, 0); stageA(2, 0, 0); stageA(3, 0, 0);
#pragma unroll
  for (int u = 0; u < NB; ++u) stageB(u, 0, 0);
#pragma unroll
  for (int u = 0; u < NB; ++u) stageB(u, 1, 1);
  WAIT_NB();
  __builtin_amdgcn_s_barrier();

  for (int t = 0; t < NT; ++t) {
    const int s = t & 1;
    const int ktA = (t + 1 < NT) ? t + 1 : NT - 1;
    const int ktB = (t + 2 < NT) ? t + 2 : NT - 1;

    // ---- P1: rd afA+bfr0; stage A(t+1)u0,u1; MFMA (mh0,nh0) ----
#pragma unroll
    for (int mf = 0; mf < 2; ++mf)
#pragma unroll
      for (int ks = 0; ks < 2; ++ks) afA[mf][ks] = rdA(s, 0, mf, ks);
#pragma unroll
    for (int nf = 0; nf < NF; ++nf)
#pragma unroll
      for (int ks = 0; ks < 2; ++ks) bfr0[nf][ks] = rdB(s, 0, nf, ks);
    stageA(0, s ^ 1, ktA); stageA(1, s ^ 1, ktA);
    __builtin_amdgcn_s_barrier();
    asm volatile("s_waitcnt lgkmcnt(0)" ::: "memory");
    __builtin_amdgcn_sched_barrier(0);
    __builtin_amdgcn_s_setprio(1);
#pragma unroll
    for (int mf = 0; mf < 2; ++mf)
#pragma unroll
      for (int nf = 0; nf < NF; ++nf) {
        acc[mf][nf] = __builtin_amdgcn_mfma_f32_16x16x32_bf16(afA[mf][0], bfr0[nf][0], acc[mf][nf], 0, 0, 0);
        acc[mf][nf] = __builtin_amdgcn_mfma_f32_16x16x32_bf16(afA[mf][1], bfr0[nf][1], acc[mf][nf], 0, 0, 0);
      }
    __builtin_amdgcn_s_setprio(0);
    __builtin_amdgcn_s_barrier();

    // ---- P2: rd bfr1; stage A(t+1)u2,u3; MFMA (mh0,nh1) ----
#pragma unroll
    for (int nf = 0; nf < NF; ++nf)
#pragma unroll
      for (int ks = 0; ks < 2; ++ks) bfr1[nf][ks] = rdB(s, 1, nf, ks);
    stageA(2, s ^ 1, ktA); stageA(3, s ^ 1, ktA);
    __builtin_amdgcn_s_barrier();
    asm volatile("s_waitcnt lgkmcnt(0)" ::: "memory");
    __builtin_amdgcn_sched_barrier(0);
    __builtin_amdgcn_s_setprio(1);
#pragma unroll
    for (int mf = 0; mf < 2; ++mf)
#pragma unroll
      for (int nf = 0; nf < NF; ++nf) {
        acc[mf][NF + nf] = __builtin_amdgcn_mfma_f32_16x16x32_bf16(afA[mf][0], bfr1[nf][0], acc[mf][NF + nf], 0, 0, 0);
        acc[mf][NF + nf] = __builtin_amdgcn_mfma_f32_16x16x32_bf16(afA[mf][1], bfr1[nf][1], acc[mf][NF + nf], 0, 0, 0);
      }
    __builtin_amdgcn_s_setprio(0);
    __builtin_amdgcn_s_barrier();

    // ---- P3: rd afB; stage B(t+2) units 0..NB-2; MFMA (mh1,nh0) ----
#pragma unroll
    for (int mf = 0; mf < 2; ++mf)
#pragma unroll
      for (int ks = 0; ks < 2; ++ks) afB[mf][ks] = rdA(s, 1, mf, ks);
#pragma unroll
    for (int u = 0; u < NB - 1; ++u) stageB(u, s, ktB);
    __builtin_amdgcn_s_barrier();
    asm volatile("s_waitcnt lgkmcnt(0)" ::: "memory");
    __builtin_amdgcn_sched_barrier(0);
    __builtin_amdgcn_s_setprio(1);
#pragma unroll
    for (int mf = 0; mf < 2; ++mf)
#pragma unroll
      for (int nf = 0; nf < NF; ++nf) {
        acc[2 + mf][nf] = __builtin_amdgcn_mfma_f32_16x16x32_bf16(afB[mf][0], bfr0[nf][0], acc[2 + mf][nf], 0, 0, 0);
        acc[2 + mf][nf] = __builtin_amdgcn_mfma_f32_16x16x32_bf16(afB[mf][1], bfr0[nf][1], acc[2 + mf][nf], 0, 0, 0);
      }
    __builtin_amdgcn_s_setprio(0);
    __builtin_amdgcn_s_barrier();

    // ---- P4: stage B(t+2) last unit; MFMA (mh1,nh1); vmcnt(NB) ----
    stageB(NB - 1, s, ktB);
    __builtin_amdgcn_s_barrier();
    __builtin_amdgcn_s_setprio(1);
#pragma unroll
    for (int mf = 0; mf < 2; ++mf)
#pragma unroll
      for (int nf = 0; nf < NF; ++nf) {
        acc[2 + mf][NF + nf] = __builtin_amdgcn_mfma_f32_16x16x32_bf16(afB[mf][0], bfr1[nf][0], acc[2 + mf][NF + nf], 0, 0, 0);
        acc[2 + mf][NF + nf] = __builtin_amdgcn_mfma_f32_16x16x32_bf16(afB[mf][1], bfr1[nf][1], acc[2 + mf][NF + nf], 0, 0, 0);
      }
    __builtin_amdgcn_s_setprio(0);
    WAIT_NB();                              // A(t+1)+B(t+1) resident
    __builtin_amdgcn_s_barrier();
  }

  asm volatile("s_waitcnt vmcnt(0)" ::: "memory");     // drain tail dummies

#pragma unroll
  for (int mi = 0; mi < 4; ++mi)
#pragma unroll
    for (int ni = 0; ni < 2 * NF; ++ni) {
      int row = bm + wm * 64 + mi * 16 + l4 * 4;
      int col = bn + wn * 2 * HN + ni * 16 + l15;
      if constexpr (BF16OUT) {
        u16* dst = (u16*)Cv;
#pragma unroll
        for (int j = 0; j < 4; ++j)
          dst[(size_t)(row + j) * N + col] = f2bf(acc[mi][ni][j]);
      } else {
        float* p = (float*)Cv + (size_t)row * N + col;
        p[0] = acc[mi][ni][0];
        p[(size_t)N] = acc[mi][ni][1];
        p[2 * (size_t)N] = acc[mi][ni][2];
        p[3 * (size_t)N] = acc[mi][ni][3];
      }
    }
#undef WAIT_NB
}

// ---------------- RMSNorm + RoPE + layout (bf16 qkv in; Q scaled; V transposed) -------
__global__ __launch_bounds__(256) void rope_kernel(const u16* __restrict__ qkv,
                                                   const float* __restrict__ cosb,
                                                   const float* __restrict__ sinb,
                                                   const float* __restrict__ qw,
                                                   const float* __restrict__ kw,
                                                   u16* __restrict__ Qo,
                                                   u16* __restrict__ Ko,
                                                   u16* __restrict__ Vt) {
  int wid = threadIdx.x >> 6, lane = threadIdx.x & 63;
  int item = blockIdx.x * 4 + wid;          // item = t*48 + hid
  int t = item / 48, hid = item % 48;
  const u16* x = qkv + (size_t)t * 6144 + hid * 128;
  float x1 = bf2f(x[lane]), x2 = bf2f(x[lane + 64]);
  if (hid < NQ + NKV) {
    float ss = x1 * x1 + x2 * x2;
    for (int off = 32; off; off >>= 1) ss += __shfl_xor(ss, off);
    float inv = rsqrtf(ss * (1.0f / 128.0f) + 1e-6f);
    const float* wn = (hid < NQ) ? qw : kw;
    float n1 = x1 * inv * wn[lane], n2 = x2 * inv * wn[lane + 64];
    float c1 = cosb[t * 128 + lane], s1 = sinb[t * 128 + lane];
    float c2 = cosb[t * 128 + lane + 64], s2 = sinb[t * 128 + lane + 64];
    float o1 = n1 * c1 - n2 * s1;
    float o2 = n2 * c2 + n1 * s2;
    if (hid < NQ) {
      const float scale = 0.08838834764831845f;  // fold 1/sqrt(128) into Q
      u16* q = Qo + ((size_t)hid * T_SEQ + t) * 128;
      q[lane] = f2bf(o1 * scale); q[lane + 64] = f2bf(o2 * scale);
    } else {
      int h = hid - NQ;
      u16* k = Ko + ((size_t)h * T_SEQ + t) * 128;
      k[lane] = f2bf(o1); k[lane + 64] = f2bf(o2);
    }
  } else {
    int h = hid - (NQ + NKV);
    Vt[((size_t)h * 128 + lane) * T_SEQ + t] = x[lane];
    Vt[((size_t)h * 128 + lane + 64) * T_SEQ + t] = x[lane + 64];
  }
}

#define WAITVM4() asm volatile("s_waitcnt vmcnt(4)" ::: "memory")
#define WAITVM0() asm volatile("s_waitcnt vmcnt(0)" ::: "memory")

// ---------------- flash attention: 4 waves/block, QBLK=64, KBLK=32, LDS dbuf ----------------
__global__ __launch_bounds__(256) void attn_kernel(const u16* __restrict__ Q,
                                                   const u16* __restrict__ Kb,
                                                   const u16* __restrict__ Vt,
                                                   u16* __restrict__ O) {
  __shared__ u16 kls[2][32 * 128];   // swizzled: chunk16 ^= (row&7)
  __shared__ u16 vls[2][128 * 32];   // swizzled: chunk16 ^= ((d>>1)&3)
  __shared__ u16 plds[4][16 * 40];   // per-wave P buffer [16 q][32 k] pad to 40

  const int tid = threadIdx.x;
  const int lane = tid & 63, w = tid >> 6;
  const int l15 = lane & 15, l4 = lane >> 4;
  const int h = blockIdx.x;          // q head
  const int q0 = blockIdx.y * 64;    // block q base
  const int wq0 = q0 + w * 16;       // wave q base
  const int kvh = h >> 2;

  bf16x8 qf[4];
  {
    const u16* qrow = Q + ((size_t)h * T_SEQ + (wq0 + l15)) * DH;
    for (int ks = 0; ks < 4; ++ks)
      qf[ks] = *(const bf16x8*)(qrow + ks * 32 + l4 * 8);
  }

  f32x4 acc[8] = {};
  float m = -1e30f, lsum = 0.f;

  int ks0 = q0 - (WIN - 1); if (ks0 < 0) ks0 = 0;
  ks0 &= ~31;
  const int kend = q0 + 32;

  auto stage = [&](int b, int k0) {
    for (int c = 0; c < 2; ++c) {
      int base = w * 2048 + c * 1024;            // bytes in 8KB tile
      int idx = base / 16 + lane;                // 16B chunk index
      {
        int row = idx >> 4;                      // K row (32 rows x 256B)
        int col = (idx & 15) ^ (row & 7);
        gload16(Kb + ((size_t)kvh * T_SEQ + k0 + row) * DH + col * 8,
                (char*)kls[b] + base);
      }
      {
        int d = idx >> 2;                        // V^T row (128 rows x 64B)
        int ch = (idx & 3) ^ ((d >> 1) & 3);
        gload16(Vt + ((size_t)kvh * DH + d) * T_SEQ + k0 + ch * 8,
                (char*)vls[b] + base);
      }
    }
  };

  stage(0, ks0);
  int buf = 0;
  for (int k0 = ks0; k0 <= kend; k0 += 32) {
    bool more = (k0 + 32 <= kend);
    if (more) stage(buf ^ 1, k0 + 32);
    if (more) { WAITVM4(); } else { WAITVM0(); }
    __builtin_amdgcn_s_barrier();
    __builtin_amdgcn_sched_barrier(0);

    if (k0 <= wq0 + 15 && k0 + 31 >= wq0 - (WIN - 1)) {
      f32x4 st[2];
      for (int kh = 0; kh < 2; ++kh) {
        f32x4 s = {};
        int row = kh * 16 + l15;
        const char* kb = (const char*)kls[buf] + row * 256;
        for (int ks = 0; ks < 4; ++ks) {
          int chunk = (ks * 4 + l4) ^ (row & 7);
          bf16x8 kf = *(const bf16x8*)(kb + chunk * 16);
          s = __builtin_amdgcn_mfma_f32_16x16x32_bf16(kf, qf[ks], s, 0, 0, 0);
        }
        st[kh] = s;
      }
      const int q = wq0 + l15;
      float pv[2][4];
      float mx = -3e38f;
      for (int kh = 0; kh < 2; ++kh)
        for (int i = 0; i < 4; ++i) {
          int k = k0 + kh * 16 + l4 * 4 + i;
          bool ok = ((k >> 2) <= (q >> 2)) && (q - k < WIN);
          float s = ok ? st[kh][i] : -3e38f;
          pv[kh][i] = s;
          mx = fmaxf(mx, s);
        }
      mx = fmaxf(mx, __shfl_xor(mx, 16));
      mx = fmaxf(mx, __shfl_xor(mx, 32));
      if (!__all(mx <= m + 8.f)) {
        float mn = fmaxf(m, mx);
        float sc = __expf(m - mn);
        m = mn;
        lsum *= sc;
        for (int nt = 0; nt < 8; ++nt)
          for (int i = 0; i < 4; ++i) acc[nt][i] *= sc;
      }
      float rs = 0.f;
      for (int kh = 0; kh < 2; ++kh)
        for (int i = 0; i < 4; ++i) {
          float p = __expf(pv[kh][i] - m);
          pv[kh][i] = p;
          rs += p;
        }
      rs += __shfl_xor(rs, 16);
      rs += __shfl_xor(rs, 32);
      lsum += rs;
      u16* pw = plds[w];
      for (int kh = 0; kh < 2; ++kh) {
        unsigned int d0 = (unsigned int)f2bf(pv[kh][0]) | ((unsigned int)f2bf(pv[kh][1]) << 16);
        unsigned int d1 = (unsigned int)f2bf(pv[kh][2]) | ((unsigned int)f2bf(pv[kh][3]) << 16);
        *(unsigned int*)(pw + l15 * 40 + kh * 16 + l4 * 4) = d0;
        *(unsigned int*)(pw + l15 * 40 + kh * 16 + l4 * 4 + 2) = d1;
      }
      bf16x8 pf = *(const bf16x8*)(pw + l15 * 40 + l4 * 8);
      for (int nt = 0; nt < 8; ++nt) {
        int d = nt * 16 + l15;
        int chunk = l4 ^ ((d >> 1) & 3);
        bf16x8 vf = *(const bf16x8*)((const char*)vls[buf] + d * 64 + chunk * 16);
        acc[nt] = __builtin_amdgcn_mfma_f32_16x16x32_bf16(vf, pf, acc[nt], 0, 0, 0);
      }
    }
    __builtin_amdgcn_sched_barrier(0);
    __builtin_amdgcn_s_barrier();
    buf ^= 1;
  }

  float inv = 1.0f / lsum;
  for (int nt = 0; nt < 8; ++nt) {
    u16x4 o;
    for (int i = 0; i < 4; ++i) o[i] = f2bf(acc[nt][i] * inv);
    *(u16x4*)(O + (size_t)(wq0 + l15) * (NQ * DH) + h * DH + nt * 16 + l4 * 4) = o;
  }
}

extern "C" void kernel_launch(void* const* d_in, const int* in_sizes, int n_in,
                              void* d_out, int out_size, void* d_ws, size_t ws_size,
                              hipStream_t stream) {
  const float* hidden = (const float*)d_in[0];
  const float* cosb   = (const float*)d_in[1];
  const float* sinb   = (const float*)d_in[2];
  const float* w_qkv  = (const float*)d_in[3];
  const float* qnw    = (const float*)d_in[4];
  const float* knw    = (const float*)d_in[5];
  const float* w_o    = (const float*)d_in[6];
  float* out = (float*)d_out;
  char* ws = (char*)d_ws;

  u16*   wqkvT  = (u16*)(ws);                        // [0, 48M)
  u16*   hid_bf = (u16*)(ws + ((size_t)48 << 20));   // [48M, 64M)
  u16*   qkv_bf = (u16*)(ws + ((size_t)64 << 20));   // [64M, 88M) bf16 qkv (24MB)
  u16*   q_bf   = (u16*)(ws + ((size_t)112 << 20));  // 16MB
  u16*   k_bf   = (u16*)(ws + ((size_t)128 << 20));  // 4MB
  u16*   vt_bf  = (u16*)(ws + ((size_t)132 << 20));  // 4MB
  u16*   attn_bf= (u16*)(ws + ((size_t)48 << 20));   // reuse hid_bf region
  u16*   woT    = (u16*)(ws);                        // reuse wqkvT region

  f32_to_bf16<<<4096, 256, 0, stream>>>(hidden, hid_bf, T_SEQ * HID);
  transpose_f32_to_bf16<<<dim3(192, 128), dim3(32, 8), 0, stream>>>(w_qkv, wqkvT, HID, 6144);
  // gemm1: 2048x6144x4096, BN=192 -> grid 8x32 = 256 blocks (full fill), bf16 out
  gemm_np<3, true><<<256, 512, 0, stream>>>(hid_bf, wqkvT, qkv_bf, 6144, HID, 64);
  transpose_f32_to_bf16<<<dim3(128, 128), dim3(32, 8), 0, stream>>>(w_o, woT, NQ * DH, HID);
  rope_kernel<<<(T_SEQ * 48) / 4, 256, 0, stream>>>(qkv_bf, cosb, sinb, qnw, knw, q_bf, k_bf, vt_bf);
  attn_kernel<<<dim3(NQ, T_SEQ / 64), 256, 0, stream>>>(q_bf, k_bf, vt_bf, attn_bf);
  // gemm2: 2048x4096x4096, BN=128 -> grid 8x32 = 256 blocks (full fill), f32 out
  gemm_np<2, false><<<256, 512, 0, stream>>>(attn_bf, woT, out, HID, NQ * DH, 64);
}